// Round 1
// baseline (117.194 us; speedup 1.0000x reference)
//
#include <hip/hip_runtime.h>
#include <stdint.h>

#define B_DIM 4096
#define C_DIM 9605
#define NT 512
#define NW (NT / 64)
#define VEC_END 8192           // 4 * NT * 4 elements covered by vectorized loop
#define TOPK_N 10
#define EPS_F 1e-8f
#define LOG2E_F 1.4426950408889634f
#define LN2_F 0.6931471805599453f
#define CLIP_F 0.05f

typedef float f4u __attribute__((ext_vector_type(4), aligned(4)));

__device__ __forceinline__ float sigmoid_f(float x) {
  float e = __builtin_amdgcn_exp2f(-x * LOG2E_F);       // v_exp_f32
  return __builtin_amdgcn_rcpf(1.0f + e);               // v_rcp_f32
}

// base loss term (before mult), y assumed exactly 0.0 or 1.0
__device__ __forceinline__ float loss_term(float s, float yv) {
  bool pos = (yv != 0.0f);
  float xn = fminf(1.0f - s + CLIP_F, 1.0f);            // xs_neg
  float z = pos ? fmaxf(s, EPS_F) : fmaxf(xn, EPS_F);   // log argument
  float logz = __builtin_amdgcn_logf(z) * LN2_F;        // v_log_f32 (log2) -> ln
  float t = fmaxf(s - CLIP_F, 0.0f);                    // 1 - xs_neg
  float t2 = t * t;
  float w = pos ? (1.0f - s) : (t2 * t2);               // (1-pt)^gamma
  return logz * w;
}

__device__ __forceinline__ unsigned long long make_key(float s, int c) {
  // s > 0 always (sigmoid), so float bits are order-preserving.
  // ~c in low bits => on value ties, larger ~c = smaller index wins (jax top_k).
  return ((unsigned long long)__float_as_uint(s) << 32) | (uint32_t)(~(uint32_t)c);
}

__device__ __forceinline__ unsigned long long rescan_chunk(const float* xs, int tid) {
  unsigned long long bk = 0ull;
#pragma unroll
  for (int k = 0; k < 4; ++k) {
    int base = (k * NT + tid) * 4;
#pragma unroll
    for (int j = 0; j < 4; ++j) {
      unsigned long long key = make_key(xs[base + j], base + j);
      bk = bk > key ? bk : key;
    }
  }
  for (int c = VEC_END + tid; c < C_DIM; c += NT) {
    unsigned long long key = make_key(xs[c], c);
    bk = bk > key ? bk : key;
  }
  return bk;
}

__global__ __launch_bounds__(NT, 8) void asym_loss_row_kernel(
    const float* __restrict__ x, const float* __restrict__ y,
    const unsigned char* __restrict__ wl_mask,
    const int* __restrict__ compost, const int* __restrict__ recycle,
    const int* __restrict__ donate, float* __restrict__ row_out) {
  __shared__ float xs[C_DIM];
  __shared__ unsigned long long s_wkey[NW];
  __shared__ unsigned long long s_winner;
  __shared__ int s_gtany;
  __shared__ float s_part[NW];

  const int row = blockIdx.x;
  const int tid = threadIdx.x;
  const int lane = tid & 63;
  const int wid = tid >> 6;
  const float* xr = x + (size_t)row * C_DIM;
  const float* yr = y + (size_t)row * C_DIM;

  if (tid == 0) s_gtany = 0;
  __syncthreads();

  // ---- gt_none: does this row's y hit any of the 210 whitelist indices? ----
  if (tid < 210) {
    int idx = (tid < 70) ? compost[tid]
            : (tid < 140) ? recycle[tid - 70]
                          : donate[tid - 140];
    if (yr[idx] != 0.0f) atomicOr(&s_gtany, 1);
  }

  // ---- Phase A: streamed loss + stash sigmoid in LDS + local argmax key ----
  float lsum = 0.0f;
  unsigned long long bestkey = 0ull;

  f4u xv[4], yv[4];
#pragma unroll
  for (int k = 0; k < 4; ++k) {
    int c = (k * NT + tid) * 4;
    xv[k] = *(const f4u*)(xr + c);
    yv[k] = *(const f4u*)(yr + c);
  }
#pragma unroll
  for (int k = 0; k < 4; ++k) {
    int c = (k * NT + tid) * 4;
    f4u sv;
#pragma unroll
    for (int j = 0; j < 4; ++j) {
      float s = sigmoid_f(xv[k][j]);
      sv[j] = s;
      lsum += loss_term(s, yv[k][j]);
      unsigned long long key = make_key(s, c + j);
      bestkey = bestkey > key ? bestkey : key;
    }
    *(f4u*)(&xs[c]) = sv;  // 16B-aligned LDS store
  }
  for (int c = VEC_END + tid; c < C_DIM; c += NT) {
    float s = sigmoid_f(xr[c]);
    xs[c] = s;
    lsum += loss_term(s, yr[c]);
    unsigned long long key = make_key(s, c);
    bestkey = bestkey > key ? bestkey : key;
  }
  __syncthreads();
  const bool gt_none = (s_gtany == 0);

  // ---- Phase B: 10 rounds of block-wide argmax with exclusion ----
  int my_wc = -1;
  float my_wv = 0.0f;
#pragma unroll 1
  for (int r = 0; r < TOPK_N; ++r) {
    unsigned long long k = bestkey;
#pragma unroll
    for (int off = 32; off; off >>= 1) {
      unsigned long long o = __shfl_down(k, off, 64);
      k = k > o ? k : o;
    }
    if (lane == 0) s_wkey[wid] = k;
    __syncthreads();
    if (tid == 0) {
      unsigned long long m = s_wkey[0];
#pragma unroll
      for (int w2 = 1; w2 < NW; ++w2) m = m > s_wkey[w2] ? m : s_wkey[w2];
      s_winner = m;
    }
    __syncthreads();
    unsigned long long wk = s_winner;
    int wc = (int)(~(uint32_t)wk);
    if (tid == r) {
      my_wc = wc;
      my_wv = __uint_as_float((uint32_t)(wk >> 32));
    }
    // owner of the winning index excludes it and rescans its chunk
    int own = (wc < VEC_END) ? ((wc >> 2) & (NT - 1)) : ((wc - VEC_END) & (NT - 1));
    if (own == tid) {
      xs[wc] = 0.0f;
      bestkey = rescan_chunk(xs, tid);
    }
    __syncthreads();
  }

  // ---- Phase C: penalty extras (threads 0..9 each own one winner) ----
  if (tid < TOPK_N && my_wc >= 0) {
    float yv2 = yr[my_wc];
    bool wl = (wl_mask[my_wc] != 0);
    bool pen = wl ? (yv2 == 0.0f) : gt_none;
    if (pen) lsum += loss_term(my_wv, yv2);  // mult=2 => one extra copy
  }

  // ---- Phase D: block reduce -> per-row partial ----
  float v = lsum;
#pragma unroll
  for (int off = 32; off; off >>= 1) v += __shfl_down(v, off, 64);
  if (lane == 0) s_part[wid] = v;
  __syncthreads();
  if (tid == 0) {
    float tot = 0.0f;
#pragma unroll
    for (int w2 = 0; w2 < NW; ++w2) tot += s_part[w2];
    row_out[row] = tot;
  }
}

__global__ void finalize_kernel(const float* __restrict__ row_out,
                                float* __restrict__ out) {
  const int tid = threadIdx.x;  // 256 threads, 1 block
  const int lane = tid & 63;
  const int wid = tid >> 6;
  __shared__ double sp[4];
  double acc = 0.0;
  for (int i = tid; i < B_DIM; i += 256) acc += (double)row_out[i];
#pragma unroll
  for (int off = 32; off; off >>= 1) acc += __shfl_down(acc, off, 64);
  if (lane == 0) sp[wid] = acc;
  __syncthreads();
  if (tid == 0) {
    double t = sp[0] + sp[1] + sp[2] + sp[3];
    out[0] = (float)(-t);
  }
}

extern "C" void kernel_launch(void* const* d_in, const int* in_sizes, int n_in,
                              void* d_out, int out_size, void* d_ws, size_t ws_size,
                              hipStream_t stream) {
  (void)in_sizes; (void)n_in; (void)out_size; (void)ws_size;
  const float* x = (const float*)d_in[0];
  const float* y = (const float*)d_in[1];
  const unsigned char* wl = (const unsigned char*)d_in[2];  // numpy bool = 1 byte
  const int* compost = (const int*)d_in[3];
  const int* recycle = (const int*)d_in[4];
  const int* donate  = (const int*)d_in[5];
  float* row_part = (float*)d_ws;  // 4096 floats

  asym_loss_row_kernel<<<B_DIM, NT, 0, stream>>>(x, y, wl, compost, recycle,
                                                 donate, row_part);
  finalize_kernel<<<1, 256, 0, stream>>>(row_part, (float*)d_out);
}

// Round 2
// 66.337 us; speedup vs baseline: 1.7666x; 1.7666x over previous
//
#include <hip/hip_runtime.h>
#include <stdint.h>

#define B_DIM 4096
#define C_DIM 9605
#define NT 512
#define NW (NT / 64)
#define VEC_N 8192             // 4 * NT * 4 elements covered by vectorized loop
#define TOPK_N 10
#define CAP 1024               // candidate list capacity
#define EPS_F 1e-8f
#define LOG2E_F 1.4426950408889634f
#define LN2_D 0.6931471805599453
#define CLIP_F 0.05f
#define XTHRESH 2.5f           // candidate gate on raw x (sigmoid is monotone)

typedef float f4a __attribute__((ext_vector_type(4), aligned(16)));

__device__ __forceinline__ float sigmoid_f(float x) {
  float e = __builtin_amdgcn_exp2f(-x * LOG2E_F);       // v_exp_f32
  return __builtin_amdgcn_rcpf(1.0f + e);               // v_rcp_f32
}

// base loss term in log2 units (caller multiplies total by ln2)
__device__ __forceinline__ float loss2_term(float s, bool pos) {
  float xn = fminf(1.0f + CLIP_F - s, 1.0f);            // xs_neg
  float z = pos ? fmaxf(s, EPS_F) : fmaxf(xn, EPS_F);
  float logz = __builtin_amdgcn_logf(z);                // v_log_f32 = log2
  float t = fmaxf(s - CLIP_F, 0.0f);                    // 1 - xs_neg
  float t2 = t * t;
  float w = pos ? (1.0f - s) : (t2 * t2);               // (1-pt)^gamma
  return logz * w;
}

// key = s_bits(31) | ~c(14) | y(1).  s>=0 so float bits are order-preserving;
// ~c => on s ties, smaller index wins (jax top_k tie-break); y never decisive.
__device__ __forceinline__ unsigned long long make_key(float s, int c, bool pos) {
  return ((unsigned long long)__float_as_uint(s) << 15)
       | (unsigned long long)(((uint32_t)(c ^ 0x3FFF) << 1) | (pos ? 1u : 0u));
}

__device__ __forceinline__ void process_elem(float xval, float yval, int c,
                                             float& lsum,
                                             unsigned long long* cand, int* cnt) {
  float s = sigmoid_f(xval);
  bool pos = (yval != 0.0f);
  lsum += loss2_term(s, pos);
  if (xval > XTHRESH) {                    // ~0.62% of elements
    int slot = atomicAdd(cnt, 1);
    unsigned long long key = make_key(s, c, pos);
    if (slot < CAP) cand[slot] = key;
  }
}

__global__ __launch_bounds__(NT, 8) void asym_loss_row_kernel(
    const float* __restrict__ x, const float* __restrict__ y,
    const unsigned char* __restrict__ wl_mask,
    const int* __restrict__ compost, const int* __restrict__ recycle,
    const int* __restrict__ donate, float* __restrict__ row_out) {
  __shared__ unsigned long long cand[CAP];
  __shared__ float s_part[NW];
  __shared__ int s_cnt;
  __shared__ int s_gtany;

  const int row = blockIdx.x;
  const int tid = threadIdx.x;
  const int lane = tid & 63;
  const int wid = tid >> 6;
  const float* xr = x + (size_t)row * C_DIM;
  const float* yr = y + (size_t)row * C_DIM;

  if (tid == 0) { s_cnt = 0; s_gtany = 0; }
  __syncthreads();

  // ---- gt_none: does this row's y hit any of the 210 whitelist indices? ----
  if (tid < 210) {
    int idx = (tid < 70) ? compost[tid]
            : (tid < 140) ? recycle[tid - 70]
                          : donate[tid - 140];
    if (yr[idx] != 0.0f) atomicOr(&s_gtany, 1);
  }

  // ---- Phase A: streamed loss + candidate collection ----
  // Align to 16B: row byte base = row*38420 ≡ (row%4)*4 (mod 16); skip `a` head
  // elements scalar so the vector region starts on a 16B boundary.
  const int a = (4 - (row & 3)) & 3;
  float lsum = 0.0f;

  if (tid < a) process_elem(xr[tid], yr[tid], tid, lsum, cand, &s_cnt);

  const float* xa = xr + a;
  const float* ya = yr + a;
  f4a xv[4], yv[4];
#pragma unroll
  for (int k = 0; k < 4; ++k) {
    int c4 = (k * NT + tid) * 4;
    xv[k] = *(const f4a*)(xa + c4);
    yv[k] = *(const f4a*)(ya + c4);
  }
#pragma unroll
  for (int k = 0; k < 4; ++k) {
    int c4 = a + (k * NT + tid) * 4;
#pragma unroll
    for (int j = 0; j < 4; ++j)
      process_elem(xv[k][j], yv[k][j], c4 + j, lsum, cand, &s_cnt);
  }
  for (int c = a + VEC_N + tid; c < C_DIM; c += NT)
    process_elem(xr[c], yr[c], c, lsum, cand, &s_cnt);

  // per-wave reduce of lsum
#pragma unroll
  for (int off = 32; off; off >>= 1) lsum += __shfl_xor(lsum, off, 64);
  if (lane == 0) s_part[wid] = lsum;
  __syncthreads();

  // ---- Phase B: wave 0 only — top-10 tournament + penalty + row total ----
  if (wid == 0) {
    const int n = s_cnt;
    const bool gt_none = (s_gtany == 0);
    unsigned long long prev = ~0ull;   // all real keys are < 2^47
    unsigned long long mykey = 0ull;   // lane r holds round-r winner

    if (n >= TOPK_N && n <= CAP) {
      // fast path: descending-winner exclusion over the candidate list
#pragma unroll 1
      for (int r = 0; r < TOPK_N; ++r) {
        unsigned long long loc = 0ull;
        for (int i = lane; i < n; i += 64) {
          unsigned long long k = cand[i];
          if (k < prev && k > loc) loc = k;
        }
#pragma unroll
        for (int off = 32; off; off >>= 1) {
          unsigned long long o = __shfl_xor(loc, off, 64);
          loc = loc > o ? loc : o;
        }
        if (lane == r) mykey = loc;
        prev = loc;
      }
    } else {
      // fallback (pathological inputs only): re-read the row from global
#pragma unroll 1
      for (int r = 0; r < TOPK_N; ++r) {
        unsigned long long loc = 0ull;
        for (int i = lane; i < C_DIM; i += 64) {
          float s = sigmoid_f(xr[i]);
          unsigned long long k = make_key(s, i, yr[i] != 0.0f);
          if (k < prev && k > loc) loc = k;
        }
#pragma unroll
        for (int off = 32; off; off >>= 1) {
          unsigned long long o = __shfl_xor(loc, off, 64);
          loc = loc > o ? loc : o;
        }
        if (lane == r) mykey = loc;
        prev = loc;
      }
    }

    float extra = 0.0f;
    if (lane < TOPK_N) {
      int wc = 0x3FFF ^ (int)((mykey >> 1) & 0x3FFFull);
      bool ypos = (mykey & 1ull) != 0ull;
      float s = __uint_as_float((uint32_t)(mykey >> 15));
      bool wl = (wl_mask[wc] != 0);
      bool pen = wl ? (!ypos) : gt_none;
      if (pen) extra = loss2_term(s, ypos);  // mult=2 => one extra copy
    }
#pragma unroll
    for (int off = 32; off; off >>= 1) extra += __shfl_xor(extra, off, 64);
    if (lane == 0) {
      float tot = extra;
#pragma unroll
      for (int w2 = 0; w2 < NW; ++w2) tot += s_part[w2];
      row_out[row] = tot;   // still in log2 units
    }
  }
}

__global__ void finalize_kernel(const float* __restrict__ row_out,
                                float* __restrict__ out) {
  const int tid = threadIdx.x;  // 256 threads, 1 block
  const int lane = tid & 63;
  const int wid = tid >> 6;
  __shared__ double sp[4];
  double acc = 0.0;
  for (int i = tid; i < B_DIM; i += 256) acc += (double)row_out[i];
#pragma unroll
  for (int off = 32; off; off >>= 1) acc += __shfl_down(acc, off, 64);
  if (lane == 0) sp[wid] = acc;
  __syncthreads();
  if (tid == 0) {
    double t = sp[0] + sp[1] + sp[2] + sp[3];
    out[0] = (float)(-t * LN2_D);
  }
}

extern "C" void kernel_launch(void* const* d_in, const int* in_sizes, int n_in,
                              void* d_out, int out_size, void* d_ws, size_t ws_size,
                              hipStream_t stream) {
  (void)in_sizes; (void)n_in; (void)out_size; (void)ws_size;
  const float* x = (const float*)d_in[0];
  const float* y = (const float*)d_in[1];
  const unsigned char* wl = (const unsigned char*)d_in[2];  // numpy bool = 1 byte
  const int* compost = (const int*)d_in[3];
  const int* recycle = (const int*)d_in[4];
  const int* donate  = (const int*)d_in[5];
  float* row_part = (float*)d_ws;  // 4096 floats

  asym_loss_row_kernel<<<B_DIM, NT, 0, stream>>>(x, y, wl, compost, recycle,
                                                 donate, row_part);
  finalize_kernel<<<1, 256, 0, stream>>>(row_part, (float*)d_out);
}